// Round 10
// baseline (111.579 us; speedup 1.0000x reference)
//
#include <hip/hip_runtime.h>
#include <math.h>

// ret[t] = r[t] + g*ret[t+1]; out = (ret-mean)/(std+eps).
// R10 = R3 (best measured scan: 90us) with TLP doubled. Evidence R1-R9:
// dur tracks resident-wave count, not shuffle count / load mechanism;
// R3's barrier-forced staging bursts are the only compiler-proof MLP.
// CHUNK 8192->4096 (VPT 16), LA 2048->1024, LDS 36->18KB -> 8 blocks/CU
// = 32 waves/CU (k_norm occupancy), grid 8192.

#define GAMMA 0.99f
#define EPSN  1e-4

constexpr int BLOCK = 256;
constexpr int VPT   = 16;                  // main elements per thread
constexpr int CHUNK = BLOCK * VPT;         // 4096 per block
constexpr int LAPT  = 4;                   // lookahead elems/thread (1024 total)
constexpr int GRP   = 36;                  // 32 data + 4 pad words
constexpr int LDSW  = (CHUNK / 32) * GRP;  // 4608 words = 18 KiB -> 8 blocks/CU
constexpr int NACC  = 32;                  // atomic slot pairs

__host__ __device__ constexpr float gpow(int k) {
  double p = 1.0;
  for (int i = 0; i < k; ++i) p *= 0.99;
  return (float)p;
}

__device__ __forceinline__ int ldsw(int e) { return (e >> 5) * GRP + (e & 31); }

__device__ __forceinline__ float4 load4g(const float* __restrict__ p, long long i, long long n) {
  if (i + 3 < n) return *reinterpret_cast<const float4*>(p + i);
  float4 v = make_float4(0.f, 0.f, 0.f, 0.f);   // beyond-end == semantic zero
  if (i < n)     v.x = p[i];
  if (i + 1 < n) v.y = p[i + 1];
  if (i + 2 < n) v.z = p[i + 2];
  return v;
}

__device__ __forceinline__ void store4g(float* __restrict__ p, long long i, long long n, float4 v) {
  if (i + 3 < n) { *reinterpret_cast<float4*>(p + i) = v; return; }
  if (i < n)     p[i] = v.x;
  if (i + 1 < n) p[i + 1] = v.y;
  if (i + 2 < n) p[i + 2] = v.z;
}

__global__ __launch_bounds__(BLOCK)
void scan_stats(const float* __restrict__ r, long long n,
                double* __restrict__ acc, float* __restrict__ out) {
  __shared__ float lds[LDSW];
  __shared__ float wmA[4], wmB[4], wlA[4], wlB[4];
  __shared__ float r0[4], r1[4];

  const int tid  = threadIdx.x;
  const int lane = tid & 63, wv = tid >> 6;
  const long long base = (long long)blockIdx.x * CHUNK;

  // lookahead -> registers (4 contiguous floats/thread, 1024 total)
  const long long la0 = base + CHUNK + (long long)tid * LAPT;
  float4 l0 = load4g(r, la0, n);

  // coalesced global -> padded LDS (main chunk; barrier forces the burst)
  float4 st[4];
#pragma unroll
  for (int it = 0; it < 4; ++it) st[it] = load4g(r, base + 4 * (it * BLOCK + tid), n);
#pragma unroll
  for (int it = 0; it < 4; ++it)
    *reinterpret_cast<float4*>(&lds[ldsw(4 * (it * BLOCK + tid))]) = st[it];
  __syncthreads();                                             // barrier 1

  // per-thread contiguous segment from padded LDS
  float4 buf[4];
#pragma unroll
  for (int j = 0; j < 4; ++j)
    buf[j] = *reinterpret_cast<const float4*>(&lds[ldsw(VPT * tid + 4 * j)]);

  // per-thread affine aggregates: main (len 16) and lookahead (len 4)
  float bm = 0.f;
#pragma unroll
  for (int i = 3; i >= 0; --i) {
    bm = fmaf(GAMMA, bm, buf[i].w); bm = fmaf(GAMMA, bm, buf[i].z);
    bm = fmaf(GAMMA, bm, buf[i].y); bm = fmaf(GAMMA, bm, buf[i].x);
  }
  float bl = 0.f;
  bl = fmaf(GAMMA, bl, l0.w); bl = fmaf(GAMMA, bl, l0.z);
  bl = fmaf(GAMMA, bl, l0.y); bl = fmaf(GAMMA, bl, l0.x);

  // fused ILP-2 inclusive wave suffix scans (main + lookahead)
  float ia = gpow(VPT), ib = bm;
  float ja = gpow(LAPT), jb = bl;
#pragma unroll
  for (int d = 1; d < 64; d <<= 1) {
    float oa = __shfl_down(ia, d), ob = __shfl_down(ib, d);
    float pa = __shfl_down(ja, d), pb = __shfl_down(jb, d);
    if (lane + d < 64) {
      ib = fmaf(ia, ob, ib); ia *= oa;
      jb = fmaf(ja, pb, jb); ja *= pa;
    }
  }
  float xa = __shfl_down(ia, 1), xb = __shfl_down(ib, 1);   // wave-exclusive (main)
  if (lane == 63) { xa = 1.f; xb = 0.f; }
  if (lane == 0) { wmA[wv] = ia; wmB[wv] = ib; wlA[wv] = ja; wlB[wv] = jb; }
  __syncthreads();                                             // barrier 2

  // carry into this block's end: cblk = Wl0(Wl1(Wl2(Wl3(0))))
  float cb = 0.f;
#pragma unroll
  for (int w = 3; w >= 0; --w) cb = fmaf(wlA[w], cb, wlB[w]);
  // apply main-wave aggregates of waves > wv, then wave-exclusive map
  float cw = cb;
#pragma unroll
  for (int w = 3; w >= 1; --w)
    if (w > wv) cw = fmaf(wmA[w], cw, wmB[w]);
  float x = fmaf(xa, cw, xb);    // exact carry at end of this thread's segment

  // backward pass: produce returns + accumulate stats
  float sm = 0.f, sq = 0.f;
#pragma unroll
  for (int i = 3; i >= 0; --i) {
    x = fmaf(GAMMA, x, buf[i].w); buf[i].w = x; sm += x; sq = fmaf(x, x, sq);
    x = fmaf(GAMMA, x, buf[i].z); buf[i].z = x; sm += x; sq = fmaf(x, x, sq);
    x = fmaf(GAMMA, x, buf[i].y); buf[i].y = x; sm += x; sq = fmaf(x, x, sq);
    x = fmaf(GAMMA, x, buf[i].x); buf[i].x = x; sm += x; sq = fmaf(x, x, sq);
  }
  // write returns to own LDS slots (no hazard: per-thread ownership)
#pragma unroll
  for (int j = 0; j < 4; ++j)
    *reinterpret_cast<float4*>(&lds[ldsw(VPT * tid + 4 * j)]) = buf[j];

  // block stats reduction (ILP-2 shuffles)
#pragma unroll
  for (int d = 32; d; d >>= 1) { sm += __shfl_down(sm, d); sq += __shfl_down(sq, d); }
  if (lane == 0) { r0[wv] = sm; r1[wv] = sq; }
  __syncthreads();                                             // barrier 3

  // coalesced LDS -> global (unnormalized returns)
#pragma unroll
  for (int it = 0; it < 4; ++it) {
    const int e = 4 * (it * BLOCK + tid);
    store4g(out, base + e, n, *reinterpret_cast<const float4*>(&lds[ldsw(e)]));
  }

  if (tid == 0) {
    double S = (double)r0[0] + r0[1] + r0[2] + r0[3];
    double Q = (double)r1[0] + r1[1] + r1[2] + r1[3];
    const int slot = (blockIdx.x & (NACC - 1)) * 2;
    atomicAdd(&acc[slot], S);
    atomicAdd(&acc[slot + 1], Q);
  }
}

// pure streaming normalize: in-place on out. Zero LDS/barriers/shuffles.
__global__ void k_norm(float* __restrict__ out, long long n, const float* __restrict__ mi) {
  const float m = mi[0], inv = mi[1];
  const long long n4 = n >> 2;
  float4* p = reinterpret_cast<float4*>(out);
  long long i = (long long)blockIdx.x * blockDim.x + threadIdx.x;
  const long long stride = (long long)gridDim.x * blockDim.x;
  for (; i < n4; i += stride) {
    float4 v = p[i];
    v.x = (v.x - m) * inv; v.y = (v.y - m) * inv;
    v.z = (v.z - m) * inv; v.w = (v.w - m) * inv;
    p[i] = v;
  }
  if (blockIdx.x == 0 && threadIdx.x == 0) {          // scalar tail (n%4)
    for (long long t = n4 << 2; t < n; ++t) out[t] = (out[t] - m) * inv;
  }
}

__global__ void k_zero(double* __restrict__ acc) {
  const int t = threadIdx.x;
  if (t < 2 * NACC) acc[t] = 0.0;
}

__global__ void k_finalize(const double* __restrict__ acc, long long n, float* __restrict__ mi) {
  double S = 0.0, Q = 0.0;
  for (int i = 0; i < NACC; ++i) { S += acc[2 * i]; Q += acc[2 * i + 1]; }
  double mean = S / (double)n;
  double var  = Q / (double)n - mean * mean;
  if (var < 0.0) var = 0.0;
  mi[0] = (float)mean;
  mi[1] = (float)(1.0 / (sqrt(var) + EPSN));
}

extern "C" void kernel_launch(void* const* d_in, const int* in_sizes, int n_in,
                              void* d_out, int out_size, void* d_ws, size_t ws_size,
                              hipStream_t stream) {
  const float* r = (const float*)d_in[0];
  float* out = (float*)d_out;
  const long long n = (long long)in_sizes[0];

  double* acc = (double*)d_ws;                     // 64 doubles = 512 B
  float*  mi  = (float*)((char*)d_ws + 512);       // mean, inv_std

  const int nblk = (int)((n + CHUNK - 1) / CHUNK); // 8192 for T=2^25

  k_zero<<<1, 64, 0, stream>>>(acc);
  scan_stats<<<nblk, BLOCK, 0, stream>>>(r, n, acc, out);
  k_finalize<<<1, 1, 0, stream>>>(acc, n, mi);
  k_norm<<<2048, 256, 0, stream>>>(out, n, mi);
}